// Round 3
// baseline (265.198 us; speedup 1.0000x reference)
//
#include <hip/hip_runtime.h>

// CRF broadcast-add: out[b,l,i,j] = emission[b,l,j] + transition[i,j]
// B=32, L=512, T=64, fp32. Output = 256 MiB.
//
// v5 = DIAGNOSTIC (discriminating experiment, values unchanged):
// store the output TWICE (pass B re-stores identical values from registers,
// separated by a compiler memory barrier so neither pass is eliminated).
// Purpose: measure the kernel's true share of dur_us by subtraction.
//   dur ~285-315 -> timed window is dominated by harness poison fills
//                   (byte-conservation roofline: 1615 MB @ 6.3 TB/s = 256 us;
//                    kernel already near its 43 us floor) -> ROOFLINE.
//   dur ~330-360 -> kernel was ~95 us; doubled kernel (~190 us) should now
//                   appear in rocprof top-5 -> read FETCH_SIZE for RFO test.
//   dur ~450+    -> kernel-only timing with a real ~1 TB/s store cap.

typedef float v4f __attribute__((ext_vector_type(4)));

__global__ __launch_bounds__(256) void crf_scores_kernel(
    const float* __restrict__ emission,   // [B*L, T]   (v4f view: [16384, 16])
    const float* __restrict__ transition, // [T, T]     (v4f view: [1024])
    float* __restrict__ out)              // [B*L, T, T] (v4f view: [16384, 1024])
{
    const v4f* __restrict__ em4 = reinterpret_cast<const v4f*>(emission);
    const v4f* __restrict__ tr4 = reinterpret_cast<const v4f*>(transition);
    v4f* __restrict__ out4 = reinterpret_cast<v4f*>(out);

    const unsigned int lane = threadIdx.x & 63u;
    const unsigned int wave = threadIdx.x >> 6;          // 4 waves/block
    const unsigned int bl   = (blockIdx.x << 2) | wave;  // one bl per wave

    const v4f e = em4[(bl << 4) | (lane & 15u)];

    const v4f* __restrict__ t = tr4 + lane;
    v4f* __restrict__ o = out4 + (bl << 10) + lane;

    // compute all 16 results into registers (static indexing -> no scratch)
    v4f r[16];
#pragma unroll
    for (int it = 0; it < 16; ++it) {
        r[it] = e + t[it * 64];
    }

    // pass A
#pragma unroll
    for (int it = 0; it < 16; ++it) {
        o[it * 64] = r[it];
    }

    // keep pass A live (compiler must assume memory is observed here)
    asm volatile("" ::: "memory");

    // pass B: identical values, pure store cost
#pragma unroll
    for (int it = 0; it < 16; ++it) {
        o[it * 64] = r[it];
    }
}

extern "C" void kernel_launch(void* const* d_in, const int* in_sizes, int n_in,
                              void* d_out, int out_size, void* d_ws, size_t ws_size,
                              hipStream_t stream) {
    const float* emission   = (const float*)d_in[0]; // [32, 512, 64]
    const float* transition = (const float*)d_in[1]; // [64, 64]
    float* out = (float*)d_out;                      // [32, 512, 64, 64]

    const int block = 256;
    const int grid  = 4096;  // 16384 bl rows / 4 waves per block

    crf_scores_kernel<<<grid, block, 0, stream>>>(emission, transition, out);
}